// Round 1
// baseline (185.072 us; speedup 1.0000x reference)
//
#include <hip/hip_runtime.h>
#include <stdint.h>

// Problem constants
constexpr int NB = 8;      // batch
constexpr int NS = 2048;   // nodes
constexpr int ND = 256;    // in dim
constexpr int NDO = 256;   // out dim
constexpr int NL = 8;      // labels
constexpr int NE = 32768;  // edges per batch
constexpr int K2 = NL * ND;  // 2048 = concatenated K for the fused GEMM

typedef __attribute__((ext_vector_type(8))) short bf16x8;
typedef __attribute__((ext_vector_type(4))) float f32x4;
typedef unsigned int u32;

__device__ __forceinline__ float bf2f(uint32_t u) {
    return __uint_as_float(u << 16);
}
__device__ __forceinline__ uint16_t f2bf(float f) {
    uint32_t x = __float_as_uint(f);
    uint32_t r = (x + 0x7fffu + ((x >> 16) & 1u)) >> 16;
    return (uint16_t)r;
}

// async global->LDS, 16B per lane; lds ptr must be wave-uniform (HW adds lane*16)
__device__ __forceinline__ void gl_lds16(const void* gptr, void* lptr) {
    __builtin_amdgcn_global_load_lds(
        (const __attribute__((address_space(1))) u32*)gptr,
        (__attribute__((address_space(3))) u32*)lptr, 16, 0, 0);
}

// ---- build Wcat^T bf16: wt2[o][l*256+d] = W[l][d][o] ----
// coalesced writes; W reads strided but L2-reused (each 64B line serves 16 o's)
__global__ void convert_wt2_kernel(const float* __restrict__ W, ushort* __restrict__ wt2) {
    int j = blockIdx.x * blockDim.x + threadIdx.x;   // < NDO*K2
    int k = j & (K2 - 1);                            // l*256+d
    int o = j >> 11;
    wt2[j] = f2bf(W[(size_t)k * NDO + o]);
}

// ---- histogram over (b, tgt, lab) keys ----
__global__ void hist2_kernel(const int* __restrict__ tgt, const int* __restrict__ lab,
                             int* __restrict__ counts) {
    int i = blockIdx.x * blockDim.x + threadIdx.x;   // < NB*NE
    int b = i >> 15;                                  // NE = 32768
    atomicAdd(&counts[(b << 14) + tgt[i] * NL + lab[i]], 1);
}

// ---- per-batch exclusive scan over S*L=16384 counters (1 block/batch) ----
__global__ void scan2_kernel(const int* __restrict__ counts,
                             int* __restrict__ offsets, int* __restrict__ cursor) {
    int b = blockIdx.x;
    int t = threadIdx.x;  // 256 threads, 64 counters each
    __shared__ int part[256];
    int base = (b << 14) + t * 64;
    int s = 0;
    for (int i = 0; i < 64; i++) s += counts[base + i];
    part[t] = s;
    __syncthreads();
    if (t == 0) {
        int run = 0;
        for (int i = 0; i < 256; i++) { int v = part[i]; part[i] = run; run += v; }
    }
    __syncthreads();
    int run = part[t];
    for (int i = 0; i < 64; i++) {
        offsets[base + i] = run;
        cursor[base + i] = run;
        run += counts[base + i];
    }
}

// ---- counting-sort by (b,t,lab); payload = src only (labels are run-encoded) ----
__global__ void place2_kernel(const int* __restrict__ tgt,
                              const int* __restrict__ esrc, const int* __restrict__ elab,
                              int* __restrict__ cursor, int* __restrict__ sorted) {
    int i = blockIdx.x * blockDim.x + threadIdx.x;   // < NB*NE
    int b = i >> 15;
    int p = atomicAdd(&cursor[(b << 14) + tgt[i] * NL + elab[i]], 1);
    sorted[(b << 15) + p] = esrc[i];
}

// ---- aggregate: one wave per (b,t). Edges label-sorted -> walk runs with a
// single static accumulator; flush each label row to Z as bf16. Per-(t,l)
// counts come free from the sort offsets -> bias sum computed without edges.
// x rows read as f32 (2 MB/batch, L2-resident). ----
__global__ __launch_bounds__(256) void agg_kernel(
    const float* __restrict__ x, const float* __restrict__ bias,
    const int* __restrict__ offs, const int* __restrict__ sorted,
    ushort* __restrict__ Z, ushort* __restrict__ bsum) {
    int g = blockIdx.x * 4 + (threadIdx.x >> 6);     // (b,t) id, < NB*NS
    int lane = threadIdx.x & 63;
    int b = g >> 11;                                  // NS = 2048
    int t = g & (NS - 1);

    int off = offs[g << 3];
    int end = (t == NS - 1) ? NE : offs[(g + 1) << 3];
    // lane l<8 holds label-l start; lanes >=8 hold end (so shfl(ov,8) = end)
    int ov = (lane < 8) ? offs[(g << 3) + lane] : end;
    int n = end - off;

    const int* ep = sorted + ((size_t)b << 15) + off;
    const float4* x4 = (const float4*)x + (size_t)b * NS * 64;
    ushort* zrow = Z + (size_t)g * K2;

    float4 a; a.x = a.y = a.z = a.w = 0.f;
    int cur = 0;
    int onext = __shfl(ov, 1);
    int p = off;
    for (int base = 0; base < n; base += 64) {
        int m = n - base;
        if (m > 64) m = 64;
        int my = (lane < m) ? ep[base + lane] : 0;   // one vector load for 64 srcs
        for (int k = 0; k < m; k++) {
            while (p >= onext) {                     // label run ended: flush row
                ushort4 ob;
                ob.x = f2bf(a.x); ob.y = f2bf(a.y); ob.z = f2bf(a.z); ob.w = f2bf(a.w);
                ((ushort4*)(zrow + cur * ND))[lane] = ob;
                a.x = a.y = a.z = a.w = 0.f;
                cur++;
                onext = __shfl(ov, cur + 1);
            }
            int src = __shfl(my, k);
            float4 xv = x4[src * 64 + lane];
            a.x += xv.x; a.y += xv.y; a.z += xv.z; a.w += xv.w;
            p++;
        }
    }
    for (; cur < 8; cur++) {                         // flush tail rows (zeros after first)
        ushort4 ob;
        ob.x = f2bf(a.x); ob.y = f2bf(a.y); ob.z = f2bf(a.z); ob.w = f2bf(a.w);
        ((ushort4*)(zrow + cur * ND))[lane] = ob;
        a.x = a.y = a.z = a.w = 0.f;
    }

    // bias contribution: sum_l cnt[l] * bias[l][:]
    float4 ab; ab.x = ab.y = ab.z = ab.w = 0.f;
#pragma unroll
    for (int l = 0; l < 8; l++) {
        int c0 = __shfl(ov, l);
        int c1 = __shfl(ov, l + 1);
        float cf = (float)(c1 - c0);
        float4 bv = ((const float4*)bias)[l * 64 + lane];
        ab.x += cf * bv.x; ab.y += cf * bv.y; ab.z += cf * bv.z; ab.w += cf * bv.w;
    }
    ushort4 sb;
    sb.x = f2bf(ab.x); sb.y = f2bf(ab.y); sb.z = f2bf(ab.z); sb.w = f2bf(ab.w);
    ((ushort4*)(bsum + (size_t)g * NDO))[lane] = sb;
}

// ---- fused GEMM: out[16384x256] = relu(Z[16384x2048] @ Wcat[2048x256] + bsum)
// 64x128 tile -> 512 blocks (2/CU). 4 waves in 2x2, wave tile 32x64 (2x4 MFMA frags).
// m97 staging: unpadded stride-32 LDS + global_load_lds width 16.
// Flat grid + XCD-chunked swizzle so the 2 n-blocks sharing an A-tile share an L2.
__global__ __launch_bounds__(256) void gemm2_kernel(
    const ushort* __restrict__ Z, const ushort* __restrict__ wt2,
    const ushort* __restrict__ bsum, float* __restrict__ out) {
    // bijective XCD chunking: 512 wgs, 8 XCDs, 64 wgs/chunk
    int wgid = (blockIdx.x & 7) * 64 + (blockIdx.x >> 3);
    int m0 = (wgid >> 1) * 64;                 // S*B tile (256)
    int n0 = (wgid & 1) * 128;                 // DO tile (2)

    __shared__ ushort As[64 * 32];             // 4 KB
    __shared__ ushort Bs[128 * 32];            // 8 KB

    int tid = threadIdx.x;
    int lane = tid & 63;
    int wave = __builtin_amdgcn_readfirstlane(tid >> 6);
    int wm = wave & 1, wn = wave >> 1;
    int ln = lane & 15, quad = lane >> 4;

    f32x4 acc[2][4] = {};

    const ushort* Ag = Z + (size_t)m0 * K2;
    const ushort* Bg = wt2 + (size_t)n0 * K2;

    int r0 = tid >> 2, c0 = (tid & 3) << 3;    // chunk coords, 16B per lane

    for (int k0 = 0; k0 < K2; k0 += 32) {
        gl_lds16(Ag + (size_t)r0 * K2 + k0 + c0, &As[wave * 512]);
        gl_lds16(Bg + (size_t)r0 * K2 + k0 + c0, &Bs[wave * 512]);
        gl_lds16(Bg + (size_t)(64 + r0) * K2 + k0 + c0, &Bs[2048 + wave * 512]);
        __syncthreads();

        bf16x8 af[2], bfr[4];
        for (int i = 0; i < 2; i++)
            af[i] = *(const bf16x8*)&As[(wm * 32 + i * 16 + ln) * 32 + quad * 8];
        for (int j = 0; j < 4; j++)
            bfr[j] = *(const bf16x8*)&Bs[(wn * 64 + j * 16 + ln) * 32 + quad * 8];
        for (int i = 0; i < 2; i++)
            for (int j = 0; j < 4; j++)
                acc[i][j] = __builtin_amdgcn_mfma_f32_16x16x32_bf16(af[i], bfr[j], acc[i][j], 0, 0, 0);
        __syncthreads();
    }

    // epilogue: C/D layout col=lane&15, row=quad*4+r; fused bias + relu
    for (int j = 0; j < 4; j++) {
        int col = n0 + wn * 64 + j * 16 + ln;
        for (int i = 0; i < 2; i++) {
            int rbase = m0 + wm * 32 + i * 16 + quad * 4;
            for (int r = 0; r < 4; r++) {
                size_t idx = (size_t)(rbase + r) * NDO + col;
                float v = acc[i][j][r] + bf2f(bsum[idx]);
                out[idx] = fmaxf(v, 0.f);
            }
        }
    }
}

extern "C" void kernel_launch(void* const* d_in, const int* in_sizes, int n_in,
                              void* d_out, int out_size, void* d_ws, size_t ws_size,
                              hipStream_t stream) {
    const float* x    = (const float*)d_in[0];
    const int*   esrc = (const int*)d_in[1];
    const int*   etgt = (const int*)d_in[2];
    const int*   elab = (const int*)d_in[3];
    const float* W    = (const float*)d_in[4];
    const float* bias = (const float*)d_in[5];
    float* out = (float*)d_out;

    char* ws = (char*)d_ws;
    // workspace layout (all 1MB-aligned)
    ushort* wt2    = (ushort*)(ws);                    //  1 MB: Wcat^T bf16 [256][2048]
    ushort* Z      = (ushort*)(ws + 1048576);          // 64 MB: aggregated bf16 [16384][2048]
    ushort* bsum   = (ushort*)(ws + 68157440);         //  8 MB: bias sums bf16 [16384][256]
    int*    counts = (int*)(ws + 76546048);            //  2 MB: (b,t,l) histogram
    int*    offs   = (int*)(ws + 78643200);            //  2 MB
    int*    cursor = (int*)(ws + 80740352);            //  2 MB
    int*    sorted = (int*)(ws + 82837504);            //  1 MB: src ids, (b,t,l)-sorted

    hipMemsetAsync(counts, 0, NB * NS * NL * sizeof(int), stream);

    convert_wt2_kernel<<<2048, 256, 0, stream>>>(W, wt2);          // NDO*K2/256
    hist2_kernel<<<1024, 256, 0, stream>>>(etgt, elab, counts);    // NB*NE/256
    scan2_kernel<<<NB, 256, 0, stream>>>(counts, offs, cursor);
    place2_kernel<<<1024, 256, 0, stream>>>(etgt, esrc, elab, cursor, sorted);
    agg_kernel<<<4096, 256, 0, stream>>>(x, bias, offs, sorted, Z, bsum);
    gemm2_kernel<<<512, 256, 0, stream>>>(Z, wt2, bsum, out);
}

// Round 2
// 176.852 us; speedup vs baseline: 1.0465x; 1.0465x over previous
//
#include <hip/hip_runtime.h>
#include <stdint.h>

// Problem constants
constexpr int NB = 8;      // batch
constexpr int NS = 2048;   // nodes
constexpr int ND = 256;    // in dim
constexpr int NDO = 256;   // out dim
constexpr int NL = 8;      // labels
constexpr int NE = 32768;  // edges per batch
constexpr int K2 = NL * ND;  // 2048 = concatenated K for the fused GEMM

typedef __attribute__((ext_vector_type(8))) short bf16x8;
typedef __attribute__((ext_vector_type(4))) float f32x4;
typedef unsigned int u32;

__device__ __forceinline__ float bf2f(uint32_t u) {
    return __uint_as_float(u << 16);
}
__device__ __forceinline__ uint16_t f2bf(float f) {
    uint32_t x = __float_as_uint(f);
    uint32_t r = (x + 0x7fffu + ((x >> 16) & 1u)) >> 16;
    return (uint16_t)r;
}

// async global->LDS, 16B per lane; lds ptr must be wave-uniform (HW adds lane*16)
__device__ __forceinline__ void gl_lds16(const void* gptr, void* lptr) {
    __builtin_amdgcn_global_load_lds(
        (const __attribute__((address_space(1))) u32*)gptr,
        (__attribute__((address_space(3))) u32*)lptr, 16, 0, 0);
}

// ---- fused prep: blocks [0,2048) build Wcat^T bf16; blocks [2048,3072) histogram ----
// wt2[o][l*256+d] = W[l][d][o]; coalesced writes, strided reads stay L2-resident (W=2MB)
__global__ void prep_kernel(const float* __restrict__ W, ushort* __restrict__ wt2,
                            const int* __restrict__ tgt, const int* __restrict__ lab,
                            int* __restrict__ counts) {
    int bid = blockIdx.x;
    if (bid < 2048) {
        int j = bid * 256 + threadIdx.x;             // < NDO*K2
        int k = j & (K2 - 1);                        // l*256+d
        int o = j >> 11;
        wt2[j] = f2bf(W[(size_t)k * NDO + o]);
    } else {
        int i = (bid - 2048) * 256 + threadIdx.x;    // < NB*NE
        int b = i >> 15;                             // NE = 32768
        atomicAdd(&counts[(b << 14) + tgt[i] * NL + lab[i]], 1);
    }
}

// ---- per-batch exclusive scan over S*L=16384 counters (1 block/batch) ----
// shuffle-based block scan: no serial 256-iter section
__global__ void scan2_kernel(const int* __restrict__ counts,
                             int* __restrict__ offsets, int* __restrict__ cursor) {
    int b = blockIdx.x;
    int t = threadIdx.x;  // 256 threads, 64 counters each
    int lane = t & 63, w = t >> 6;
    __shared__ int wsum[4];
    int base = (b << 14) + t * 64;
    int s = 0;
    for (int i = 0; i < 64; i += 4) {
        int4 c = *(const int4*)&counts[base + i];
        s += c.x + c.y + c.z + c.w;
    }
    int sc = s;
    for (int d = 1; d < 64; d <<= 1) {
        int u = __shfl_up(sc, d);
        if (lane >= d) sc += u;
    }
    if (lane == 63) wsum[w] = sc;
    __syncthreads();
    int run = sc - s;                                // exclusive within wave
    for (int i = 0; i < w; i++) run += wsum[i];
    for (int i = 0; i < 64; i += 4) {
        int4 c = *(const int4*)&counts[base + i];
        int4 o;
        o.x = run; o.y = o.x + c.x; o.z = o.y + c.y; o.w = o.z + c.z;
        run = o.w + c.w;
        *(int4*)&offsets[base + i] = o;
        *(int4*)&cursor[base + i]  = o;
    }
}

// ---- counting-sort by (b,t,lab); payload = src only (labels are run-encoded) ----
__global__ void place2_kernel(const int* __restrict__ tgt,
                              const int* __restrict__ esrc, const int* __restrict__ elab,
                              int* __restrict__ cursor, int* __restrict__ sorted) {
    int i = blockIdx.x * blockDim.x + threadIdx.x;   // < NB*NE
    int b = i >> 15;
    int p = atomicAdd(&cursor[(b << 14) + tgt[i] * NL + elab[i]], 1);
    sorted[(b << 15) + p] = esrc[i];
}

// ---- aggregate: one wave per (b,t). Label-major static loop over the 8 sorted
// runs (no data-dependent flush branch -> loads pipeline). Batch pinned to XCD
// via blockIdx&7 so each XCD's L2 holds exactly its 2MB x slice. ----
__global__ __launch_bounds__(256) void agg_kernel(
    const float* __restrict__ x, const float* __restrict__ bias,
    const int* __restrict__ offs, const int* __restrict__ sorted,
    ushort* __restrict__ Z, ushort* __restrict__ bsum) {
    int bid = blockIdx.x;                             // 4096 blocks
    int b = bid & 7;                                  // batch == XCD (round-robin dispatch)
    int idx = bid >> 3;                               // 0..511
    int lane = threadIdx.x & 63;
    int t = idx * 4 + (threadIdx.x >> 6);             // 0..2047
    int g = b * NS + t;

    int off = offs[g << 3];
    int end = (t == NS - 1) ? NE : offs[(g + 1) << 3];
    // lane l<8 holds label-l start; lanes >=8 hold end (so shfl(ov,8) = end)
    int ov = (lane < 8) ? offs[(g << 3) + lane] : end;
    int n = end - off;

    const int* ep = sorted + ((size_t)b << 15) + off;
    const float4* x4 = (const float4*)x + (size_t)b * NS * 64;
    ushort* zrow = Z + (size_t)g * K2;

    int cb = 0;                                       // loaded index-chunk base
    int my = (lane < n) ? ep[lane] : 0;               // chunk of up to 64 src ids

    for (int l = 0; l < 8; l++) {
        int s = __shfl(ov, l) - off;
        int e = __shfl(ov, l + 1) - off;
        float4 a; a.x = a.y = a.z = a.w = 0.f;
        for (int k = s; k < e; k++) {
            if (k == cb + 64) {                       // k is globally contiguous across runs
                cb += 64;
                int rem = n - cb;
                my = (lane < rem) ? ep[cb + lane] : 0;
            }
            int src = __shfl(my, k - cb);
            float4 xv = x4[(size_t)src * 64 + lane];
            a.x += xv.x; a.y += xv.y; a.z += xv.z; a.w += xv.w;
        }
        ushort4 ob;
        ob.x = f2bf(a.x); ob.y = f2bf(a.y); ob.z = f2bf(a.z); ob.w = f2bf(a.w);
        ((ushort4*)(zrow + l * ND))[lane] = ob;
    }

    // bias contribution: sum_l cnt[l] * bias[l][:]
    float4 ab; ab.x = ab.y = ab.z = ab.w = 0.f;
#pragma unroll
    for (int l = 0; l < 8; l++) {
        int c0 = __shfl(ov, l);
        int c1 = __shfl(ov, l + 1);
        float cf = (float)(c1 - c0);
        float4 bv = ((const float4*)bias)[l * 64 + lane];
        ab.x += cf * bv.x; ab.y += cf * bv.y; ab.z += cf * bv.z; ab.w += cf * bv.w;
    }
    ushort4 sb;
    sb.x = f2bf(ab.x); sb.y = f2bf(ab.y); sb.z = f2bf(ab.z); sb.w = f2bf(ab.w);
    ((ushort4*)(bsum + (size_t)g * NDO))[lane] = sb;
}

// ---- fused GEMM: out[16384x256] = relu(Z[16384x2048] @ Wcat[2048x256] + bsum)
// 64x128 tile -> 512 blocks (2/CU), BK=64 (16 MFMA / 12 ds_read per barrier pair).
// XOR chunk-swizzle (ch ^= r&7) applied on BOTH the global source (gl_lds writes
// linearly) and the ds_read side -> 2 lanes/bank, conflict-free at stride 128B.
// Flat grid + XCD-chunked swizzle so the 2 n-blocks sharing an A-tile share an L2.
__global__ __launch_bounds__(256) void gemm2_kernel(
    const ushort* __restrict__ Z, const ushort* __restrict__ wt2,
    const ushort* __restrict__ bsum, float* __restrict__ out) {
    // bijective XCD chunking: 512 wgs, 8 XCDs, 64 wgs/chunk
    int wgid = (blockIdx.x & 7) * 64 + (blockIdx.x >> 3);
    int m0 = (wgid >> 1) * 64;                 // S*B tile (256)
    int n0 = (wgid & 1) * 128;                 // DO tile (2)

    __shared__ ushort As[64 * 64];             //  8 KB
    __shared__ ushort Bs[128 * 64];            // 16 KB

    int tid = threadIdx.x;
    int lane = tid & 63;
    int wave = __builtin_amdgcn_readfirstlane(tid >> 6);
    int wm = wave & 1, wn = wave >> 1;
    int ln = lane & 15, quad = lane >> 4;

    f32x4 acc[2][4] = {};

    const ushort* Ag = Z + (size_t)m0 * K2;
    const ushort* Bg = wt2 + (size_t)n0 * K2;

    for (int k0 = 0; k0 < K2; k0 += 64) {
        // A: 512 16B-chunks, 2 passes; source column pre-swizzled by row
#pragma unroll
        for (int p = 0; p < 2; p++) {
            int cid = p * 256 + tid;
            int r = cid >> 3, ch = (cid & 7) ^ (r & 7);
            gl_lds16(Ag + (size_t)r * K2 + k0 + ch * 8, &As[(p * 256 + wave * 64) * 8]);
        }
        // B: 1024 chunks, 4 passes
#pragma unroll
        for (int p = 0; p < 4; p++) {
            int cid = p * 256 + tid;
            int r = cid >> 3, ch = (cid & 7) ^ (r & 7);
            gl_lds16(Bg + (size_t)r * K2 + k0 + ch * 8, &Bs[(p * 256 + wave * 64) * 8]);
        }
        __syncthreads();

        bf16x8 af[2][2], bfr[2][4];
#pragma unroll
        for (int ks = 0; ks < 2; ks++) {
#pragma unroll
            for (int i = 0; i < 2; i++) {
                int row = wm * 32 + i * 16 + ln;
                int ch = (ks * 4 + quad) ^ (row & 7);
                af[ks][i] = *(const bf16x8*)&As[row * 64 + ch * 8];
            }
#pragma unroll
            for (int j = 0; j < 4; j++) {
                int row = wn * 64 + j * 16 + ln;
                int ch = (ks * 4 + quad) ^ (row & 7);
                bfr[ks][j] = *(const bf16x8*)&Bs[row * 64 + ch * 8];
            }
        }
#pragma unroll
        for (int ks = 0; ks < 2; ks++)
            for (int i = 0; i < 2; i++)
                for (int j = 0; j < 4; j++)
                    acc[i][j] = __builtin_amdgcn_mfma_f32_16x16x32_bf16(
                        af[ks][i], bfr[ks][j], acc[i][j], 0, 0, 0);
        __syncthreads();
    }

    // epilogue: C/D layout col=lane&15, row=quad*4+r; fused bias + relu
    for (int j = 0; j < 4; j++) {
        int col = n0 + wn * 64 + j * 16 + ln;
        for (int i = 0; i < 2; i++) {
            int rbase = m0 + wm * 32 + i * 16 + quad * 4;
            for (int r = 0; r < 4; r++) {
                size_t idx = (size_t)(rbase + r) * NDO + col;
                float v = acc[i][j][r] + bf2f(bsum[idx]);
                out[idx] = fmaxf(v, 0.f);
            }
        }
    }
}

extern "C" void kernel_launch(void* const* d_in, const int* in_sizes, int n_in,
                              void* d_out, int out_size, void* d_ws, size_t ws_size,
                              hipStream_t stream) {
    const float* x    = (const float*)d_in[0];
    const int*   esrc = (const int*)d_in[1];
    const int*   etgt = (const int*)d_in[2];
    const int*   elab = (const int*)d_in[3];
    const float* W    = (const float*)d_in[4];
    const float* bias = (const float*)d_in[5];
    float* out = (float*)d_out;

    char* ws = (char*)d_ws;
    // workspace layout (all 1MB-aligned)
    ushort* wt2    = (ushort*)(ws);                    //  1 MB: Wcat^T bf16 [256][2048]
    ushort* Z      = (ushort*)(ws + 1048576);          // 64 MB: aggregated bf16 [16384][2048]
    ushort* bsum   = (ushort*)(ws + 68157440);         //  8 MB: bias sums bf16 [16384][256]
    int*    counts = (int*)(ws + 76546048);            //  2 MB: (b,t,l) histogram
    int*    offs   = (int*)(ws + 78643200);            //  2 MB
    int*    cursor = (int*)(ws + 80740352);            //  2 MB
    int*    sorted = (int*)(ws + 82837504);            //  1 MB: src ids, (b,t,l)-sorted

    hipMemsetAsync(counts, 0, NB * NS * NL * sizeof(int), stream);

    prep_kernel<<<3072, 256, 0, stream>>>(W, wt2, etgt, elab, counts);
    scan2_kernel<<<NB, 256, 0, stream>>>(counts, offs, cursor);
    place2_kernel<<<1024, 256, 0, stream>>>(etgt, esrc, elab, cursor, sorted);
    agg_kernel<<<4096, 256, 0, stream>>>(x, bias, offs, sorted, Z, bsum);
    gemm2_kernel<<<512, 256, 0, stream>>>(Z, wt2, bsum, out);
}